// Round 7
// baseline (104.339 us; speedup 1.0000x reference)
//
#include <hip/hip_runtime.h>
#include <math.h>

#define B_    16
#define D_    512
#define T_    4096
#define CBN_  1024
#define CD_   8
#define NTOK_ (B_ * T_)   // 65536

// ws float offsets
#define WS_WIN_T  0        // [512][8] w_in transposed [i][o]
#define WS_WOUT   4096     // [512][8] w_out [o][j]
#define WS_BO     8192     // [512]    b_out
#define WS_BPART  8704     // [1024]   per-block loss partials

#define OUT_OFF_LOSS 33554432               // commitment[16], then codebook[16]
#define OUT_OFF_IDX  33554464               // indices as float [65536]

// ---------------- k0: weight-norm both projections into ws -------------------
__global__ __launch_bounds__(256) void k0_prep(const float* __restrict__ v_in,
                                               const float* __restrict__ g_in,
                                               const float* __restrict__ v_out,
                                               const float* __restrict__ g_out,
                                               const float* __restrict__ b_out,
                                               float* __restrict__ ws) {
    int bid = blockIdx.x, tid = threadIdx.x;
    if (bid == 0) {
        // w_in_t[i][o] = g_in[o] * v_in[o][i] / ||v_in[o,:]||
        __shared__ float part[8][33];
        __shared__ float rn[8];
        int o = tid >> 5;       // 0..7
        int g = tid & 31;       // 0..31
        float s = 0.f;
        for (int i = g * 16; i < g * 16 + 16; ++i) { float x = v_in[o * 512 + i]; s += x * x; }
        part[o][g] = s;
        __syncthreads();
        if (tid < 8) {
            float t2 = 0.f;
            for (int gg = 0; gg < 32; ++gg) t2 += part[tid][gg];
            rn[tid] = g_in[tid] / sqrtf(t2);
        }
        __syncthreads();
        for (int ii = 0; ii < 2; ++ii) {
            int i = tid * 2 + ii;
#pragma unroll
            for (int oo = 0; oo < 8; ++oo)
                ws[WS_WIN_T + i * 8 + oo] = v_in[oo * 512 + i] * rn[oo];
        }
    } else {
        // w_out rows + b_out copy
        int o = (bid - 1) * 256 + tid;
        const float4* vr = (const float4*)(v_out + (size_t)o * 8);
        float4 va = vr[0], vb = vr[1];
        float s = va.x * va.x + va.y * va.y + va.z * va.z + va.w * va.w
                + vb.x * vb.x + vb.y * vb.y + vb.z * vb.z + vb.w * vb.w;
        float rn = g_out[o] / sqrtf(s);
        float* wo = ws + WS_WOUT + (size_t)o * 8;
        wo[0] = va.x * rn; wo[1] = va.y * rn; wo[2] = va.z * rn; wo[3] = va.w * rn;
        wo[4] = vb.x * rn; wo[5] = vb.y * rn; wo[6] = vb.z * rn; wo[7] = vb.w * rn;
        ws[WS_BO + o] = b_out[o];
    }
}

// ============ fused: in_proj + search + loss-partial + out_proj ==============
// grid 1024 x 256 threads (4 waves). Block = 64 tokens (blk>>6 = batch,
// (blk&63)*64 = t base). Wave wv: in_proj rows [wv*128,+128); search tokens
// [wv*16,+16) over full register-resident codebook; out rows [wv*128,+128).
__global__ __launch_bounds__(256) void vq_fused(const float* __restrict__ z,
                                                const float* __restrict__ b_in,
                                                const float* __restrict__ codebook,
                                                const float* __restrict__ ws,
                                                float* __restrict__ d_out,
                                                float* __restrict__ bpart) {
    __shared__ float wlds[512 * 8];     // 16 KB: w_in_t, later w_out
    __shared__ float part[4 * 64 * 9];  // 9 KB: per-wave z_e partials, stride 9
    __shared__ float enorm[64 * 12];    // 3 KB: e[8], a, nrm2, zen, pad
    __shared__ float bo[512];           // 2 KB
    __shared__ int   idxl[64];
    __shared__ float wl[4];

    int tid = threadIdx.x;
    int wv = tid >> 6;
    int l  = tid & 63;
    int blk = blockIdx.x;
    int b = blk >> 6;
    int tb = (blk & 63) << 6;

    // ---- stage w_in_t (conflict-free float4 copy) ----
    {
        const float4* wsrc = (const float4*)(ws + WS_WIN_T);
#pragma unroll
        for (int k = 0; k < 4; ++k) ((float4*)wlds)[tid + k * 256] = wsrc[tid + k * 256];
    }
    __syncthreads();

    // ---- ph1: in_proj partial; wave wv covers rows [wv*128, +128) ----
    {
        float acc[8];
#pragma unroll
        for (int j = 0; j < 8; ++j) acc[j] = 0.f;
        const float* zp = z + (size_t)b * D_ * T_ + (size_t)(wv * 128) * T_ + tb + l;
        const float4* wp = ((const float4*)wlds) + wv * 256;
#pragma unroll 8
        for (int i = 0; i < 128; ++i) {
            float v = zp[(size_t)i * T_];
            float4 wa = wp[i * 2];
            float4 wb = wp[i * 2 + 1];
            acc[0] = fmaf(wa.x, v, acc[0]); acc[1] = fmaf(wa.y, v, acc[1]);
            acc[2] = fmaf(wa.z, v, acc[2]); acc[3] = fmaf(wa.w, v, acc[3]);
            acc[4] = fmaf(wb.x, v, acc[4]); acc[5] = fmaf(wb.y, v, acc[5]);
            acc[6] = fmaf(wb.z, v, acc[6]); acc[7] = fmaf(wb.w, v, acc[7]);
        }
        float* pp = &part[(wv * 64 + l) * 9];
#pragma unroll
        for (int j = 0; j < 8; ++j) pp[j] = acc[j];
    }
    __syncthreads();

    // ---- ph2: wave0 finalizes z_e (bias + 4 partials, ascending), normalizes ----
    if (wv == 0) {
        float ze[8];
#pragma unroll
        for (int j = 0; j < 8; ++j)
            ze[j] = b_in[j] + part[l * 9 + j] + part[(64 + l) * 9 + j]
                  + part[(128 + l) * 9 + j] + part[(192 + l) * 9 + j];
        float nrm2 = ze[0] * ze[0] + ze[1] * ze[1] + ze[2] * ze[2] + ze[3] * ze[3]
                   + ze[4] * ze[4] + ze[5] * ze[5] + ze[6] * ze[6] + ze[7] * ze[7];
        float zen = fmaxf(sqrtf(nrm2), 1e-12f);
        float r = 1.0f / zen;
        float e0 = ze[0] * r, e1 = ze[1] * r, e2 = ze[2] * r, e3 = ze[3] * r;
        float e4 = ze[4] * r, e5 = ze[5] * r, e6 = ze[6] * r, e7 = ze[7] * r;
        float a = e0 * e0 + e1 * e1 + e2 * e2 + e3 * e3
                + e4 * e4 + e5 * e5 + e6 * e6 + e7 * e7;
        float* ep = &enorm[l * 12];
        ep[0] = e0; ep[1] = e1; ep[2] = e2; ep[3] = e3;
        ep[4] = e4; ep[5] = e5; ep[6] = e6; ep[7] = e7;
        ep[8] = a; ep[9] = nrm2; ep[10] = zen; ep[11] = 0.f;
    }

    // ---- codebook into registers: 16 entries/lane (e = k*64 + l), every wave ----
    float cbn[16][8]; float cc[16];
#pragma unroll
    for (int k = 0; k < 16; ++k) {
        const float* cp = codebook + (size_t)(k * 64 + l) * 8;
        float v[8]; float s = 0.f;
#pragma unroll
        for (int j = 0; j < 8; ++j) { v[j] = cp[j]; s += v[j] * v[j]; }
        float rn = 1.0f / fmaxf(sqrtf(s), 1e-12f);
        float cs = 0.f;
#pragma unroll
        for (int j = 0; j < 8; ++j) { float cn = v[j] * rn; cbn[k][j] = cn; cs += cn * cn; }
        cc[k] = cs;
    }
    __syncthreads();

    // ---- ph3: search; wave wv scans tokens [wv*16, +16) ----
    float lossAcc = 0.f;
    for (int s = 0; s < 16; ++s) {
        int tl = wv * 16 + s;
        float4 E0 = ((float4*)enorm)[tl * 3 + 0];
        float4 E1 = ((float4*)enorm)[tl * 3 + 1];
        float4 E2 = ((float4*)enorm)[tl * 3 + 2];   // a, nrm2, zen
        float e0 = E0.x, e1 = E0.y, e2 = E0.z, e3 = E0.w;
        float e4 = E1.x, e5 = E1.y, e6 = E1.z, e7 = E1.w;
        float a = E2.x, nrm2 = E2.y, zen = E2.z;

        float best = 3.4e38f; int bidx = 0x7fffffff;
#pragma unroll
        for (int k = 0; k < 16; ++k) {
            float dot = cbn[k][0] * e0;
            dot = fmaf(cbn[k][1], e1, dot);
            dot = fmaf(cbn[k][2], e2, dot);
            dot = fmaf(cbn[k][3], e3, dot);
            dot = fmaf(cbn[k][4], e4, dot);
            dot = fmaf(cbn[k][5], e5, dot);
            dot = fmaf(cbn[k][6], e6, dot);
            dot = fmaf(cbn[k][7], e7, dot);
            float dist = fmaf(dot, -2.0f, a) + cc[k];   // (a - 2*dot) + c
            int e = k * 64 + l;
            if (dist < best) { best = dist; bidx = e; }  // strict < -> first-min
        }
#pragma unroll
        for (int off = 1; off < 64; off <<= 1) {
            float ov = __shfl_xor(best, off, 64);
            int   oi = __shfl_xor(bidx, off, 64);
            if (ov < best || (ov == best && oi < bidx)) { best = ov; bidx = oi; }
        }
        // loss via reconstruction: dot=(a+cc-best)/2; loss=nrm2-2*dot*|ze|*|q|+|q|^2
        {
            const float* cq = codebook + (size_t)bidx * 8;
            float v[8]; float sw = 0.f;
#pragma unroll
            for (int j = 0; j < 8; ++j) { v[j] = cq[j]; sw += v[j] * v[j]; }
            float qn = sqrtf(sw);
            float rnq = 1.0f / fmaxf(qn, 1e-12f);
            float cs = 0.f;
#pragma unroll
            for (int j = 0; j < 8; ++j) { float cn = v[j] * rnq; cs += cn * cn; }
            float dot = (a + cs - best) * 0.5f;
            lossAcc += nrm2 - 2.0f * dot * zen * qn + sw;
        }
        if (l == 0) {
            int tok = blk * 64 + tl;
            d_out[OUT_OFF_IDX + tok] = (float)bidx;
            idxl[tl] = bidx;
        }
    }
    if (l == 0) wl[wv] = lossAcc;
    __syncthreads();
    if (tid == 0) bpart[blk] = (wl[0] + wl[1]) + (wl[2] + wl[3]);

    // ---- ph4: stage w_out + b_out (conflict-free float4/float2 copies) ----
    {
        const float4* wo4 = (const float4*)(ws + WS_WOUT);
#pragma unroll
        for (int k = 0; k < 4; ++k) ((float4*)wlds)[tid + k * 256] = wo4[tid + k * 256];
        ((float2*)bo)[tid] = ((const float2*)(ws + WS_BO))[tid];
    }
    __syncthreads();

    // ---- ph5: out; lane l <-> token, wave wv covers rows [wv*128, +128) ----
    {
        int idx = idxl[l];
        const float4* cq4 = (const float4*)(codebook + (size_t)idx * 8);
        float4 q0 = cq4[0], q1 = cq4[1];
        float* op = d_out + (size_t)b * D_ * T_ + tb + l;
#pragma unroll 8
        for (int oi = 0; oi < 128; ++oi) {
            int o = wv * 128 + oi;
            float4 wa = ((float4*)wlds)[o * 2];
            float4 wb = ((float4*)wlds)[o * 2 + 1];
            float x = bo[o];
            x = fmaf(wa.x, q0.x, x); x = fmaf(wa.y, q0.y, x);
            x = fmaf(wa.z, q0.z, x); x = fmaf(wa.w, q0.w, x);
            x = fmaf(wb.x, q1.x, x); x = fmaf(wb.y, q1.y, x);
            x = fmaf(wb.z, q1.z, x); x = fmaf(wb.w, q1.w, x);
            op[(size_t)o * T_] = x;
        }
    }
}

// ============ finalize: per-batch loss reduction =============================
__global__ __launch_bounds__(64) void vq_finalize(const float* __restrict__ bpart,
                                                  float* __restrict__ d_out) {
    int tid = threadIdx.x;
    if (tid < B_) {
        float s = 0.f;
        for (int k = 0; k < 64; ++k) s += bpart[tid * 64 + k];
        float m = s * (1.0f / (CD_ * T_));
        d_out[OUT_OFF_LOSS + tid] = m;
        d_out[OUT_OFF_LOSS + 16 + tid] = m;
    }
}

// ---------------- launch -----------------------------------------------------
extern "C" void kernel_launch(void* const* d_in, const int* in_sizes, int n_in,
                              void* d_out, int out_size, void* d_ws, size_t ws_size,
                              hipStream_t stream) {
    (void)in_sizes; (void)n_in; (void)out_size; (void)ws_size;
    const float* z        = (const float*)d_in[0];
    const float* v_in     = (const float*)d_in[1];
    const float* g_in     = (const float*)d_in[2];
    const float* b_in     = (const float*)d_in[3];
    const float* v_out    = (const float*)d_in[4];
    const float* g_out    = (const float*)d_in[5];
    const float* b_out    = (const float*)d_in[6];
    const float* codebook = (const float*)d_in[7];
    float* ws  = (float*)d_ws;
    float* out = (float*)d_out;

    hipLaunchKernelGGL(k0_prep, dim3(3), dim3(256), 0, stream,
                       v_in, g_in, v_out, g_out, b_out, ws);
    hipLaunchKernelGGL(vq_fused, dim3(NTOK_ / 64), dim3(256), 0, stream,
                       z, b_in, codebook, ws, out, ws + WS_BPART);
    hipLaunchKernelGGL(vq_finalize, dim3(1), dim3(64), 0, stream,
                       ws + WS_BPART, out);
}

// Round 8
// 93.237 us; speedup vs baseline: 1.1191x; 1.1191x over previous
//
#include <hip/hip_runtime.h>
#include <math.h>

#define B_    16
#define D_    512
#define T_    4096
#define CBN_  1024
#define CD_   8
#define NTOK_ (B_ * T_)   // 65536

// ws float offsets
#define WS_WIN_T  0         // [512][8]  w_in transposed [i][o]
#define WS_NCB    4096      // [1024][8] NEGATED normalized codebook
#define WS_QT     12288     // [1024][4] {||q||, ||q||^2, cc/2, 0}
#define WS_PCB    16384     // [1024][512] w_out @ cb^T + b_out
#define WS_BPART  540672    // [2048] per-block loss partials

#define OUT_OFF_LOSS 33554432               // commitment[16], then codebook[16]
#define OUT_OFF_IDX  33554464               // indices as float [65536]

// ---------------- k0: all precompute (w_in_t, neg-codebook, qtab, pcb) -------
__global__ __launch_bounds__(256) void k0_prep(const float* __restrict__ v_in,
                                               const float* __restrict__ g_in,
                                               const float* __restrict__ v_out,
                                               const float* __restrict__ g_out,
                                               const float* __restrict__ b_out,
                                               const float* __restrict__ codebook,
                                               float* __restrict__ ws) {
    int bid = blockIdx.x, tid = threadIdx.x;
    if (bid == 0) {
        // w_in_t[i][o] = g_in[o] * v_in[o][i] / ||v_in[o,:]||
        __shared__ float part[8][33];
        __shared__ float rn[8];
        int o = tid >> 5;       // 0..7
        int g = tid & 31;       // 0..31
        float s = 0.f;
        for (int i = g * 16; i < g * 16 + 16; ++i) { float x = v_in[o * 512 + i]; s += x * x; }
        part[o][g] = s;
        __syncthreads();
        if (tid < 8) {
            float t2 = 0.f;
            for (int gg = 0; gg < 32; ++gg) t2 += part[tid][gg];
            rn[tid] = g_in[tid] / sqrtf(t2);
        }
        __syncthreads();
        for (int ii = 0; ii < 2; ++ii) {
            int i = tid * 2 + ii;
#pragma unroll
            for (int oo = 0; oo < 8; ++oo)
                ws[WS_WIN_T + i * 8 + oo] = v_in[oo * 512 + i] * rn[oo];
        }
    } else if (bid <= 4) {
        // negated normalized codebook + {qn, sw, cc/2}
        int e = (bid - 1) * 256 + tid;
        const float* c = codebook + (size_t)e * 8;
        float v[8]; float s = 0.f;
#pragma unroll
        for (int j = 0; j < 8; ++j) { v[j] = c[j]; s += v[j] * v[j]; }
        float qn = sqrtf(s);
        float rn = 1.0f / fmaxf(qn, 1e-12f);
        float cs = 0.f;
        float* o = ws + WS_NCB + (size_t)e * 8;
#pragma unroll
        for (int j = 0; j < 8; ++j) { float cn = v[j] * rn; o[j] = -cn; cs += cn * cn; }
        float* q = ws + WS_QT + (size_t)e * 4;
        q[0] = qn; q[1] = s; q[2] = cs * 0.5f; q[3] = 0.f;
    } else {
        // pcb[e][o] = b_out[o] + sum_j w_out[o][j]*cb[e][j]
        int e = bid - 5;
        const float4* cq = (const float4*)(codebook + (size_t)e * 8);
        float4 q0 = cq[0], q1 = cq[1];
        float2 res; float* rp = &res.x;
#pragma unroll
        for (int ii = 0; ii < 2; ++ii) {
            int o = tid * 2 + ii;
            const float4* vr = (const float4*)(v_out + (size_t)o * 8);
            float4 va = vr[0], vb = vr[1];
            float s = va.x * va.x + va.y * va.y + va.z * va.z + va.w * va.w
                    + vb.x * vb.x + vb.y * vb.y + vb.z * vb.z + vb.w * vb.w;
            float rn = g_out[o] / sqrtf(s);
            float x = b_out[o];
            x = fmaf(va.x * rn, q0.x, x); x = fmaf(va.y * rn, q0.y, x);
            x = fmaf(va.z * rn, q0.z, x); x = fmaf(va.w * rn, q0.w, x);
            x = fmaf(vb.x * rn, q1.x, x); x = fmaf(vb.y * rn, q1.y, x);
            x = fmaf(vb.z * rn, q1.z, x); x = fmaf(vb.w * rn, q1.w, x);
            rp[ii] = x;
        }
        ((float2*)(ws + WS_PCB + (size_t)e * 512))[tid] = res;
    }
}

// ============ main fused kernel ==============================================
// grid 2048 x 128 threads (2 waves). Block = 32 tokens: b = blk>>7,
// tb = (blk&127)*32. ph1: 4-way K-split in_proj (partial p = wv*2 + (l>>5),
// rows [p*128,+128), lane&31 = token). ph2: lanes 0-31 finalize z_e.
// ph3: wave wv scans entries [wv*512,+512) as 8/lane (regs), butterfly per
// token. ph4: lanes 0-31 merge waves + loss, one parallel pass. ph5: pcb-
// gather out (tid>>5 = row quarter, tid&31 = token).
__global__ __launch_bounds__(128, 4) void vq_main(const float* __restrict__ z,
                                                  const float* __restrict__ b_in,
                                                  const float* __restrict__ ws,
                                                  float* __restrict__ d_out,
                                                  float* __restrict__ bpart) {
    __shared__ float part[4 * 32 * 9];   // 4.6 KB, stride 9
    __shared__ float enorm[32 * 12];     // 1.5 KB: e[8], a, nrm2, zen, pad
    __shared__ float cand_d[64];
    __shared__ int   cand_i[64];
    __shared__ int   idxl[32];

    int tid = threadIdx.x;
    int wv = tid >> 6;
    int l  = tid & 63;
    int half = l >> 5, lt = l & 31;
    int blk = blockIdx.x;
    int b = blk >> 7;
    int tb = (blk & 127) << 5;

    // ---- ph1: in_proj partial (w from global L1, uniform-addr float4) ----
    {
        float acc[8];
#pragma unroll
        for (int j = 0; j < 8; ++j) acc[j] = 0.f;
        const float* zp = z + (size_t)b * D_ * T_ + (size_t)(wv * 256 + half * 128) * T_ + tb + lt;
        const float4* wp = ((const float4*)(ws + WS_WIN_T)) + (wv * 256 + half * 128) * 2;
#pragma unroll 8
        for (int i = 0; i < 128; ++i) {
            float v = zp[(size_t)i * T_];
            float4 wa = wp[i * 2];
            float4 wb = wp[i * 2 + 1];
            acc[0] = fmaf(wa.x, v, acc[0]); acc[1] = fmaf(wa.y, v, acc[1]);
            acc[2] = fmaf(wa.z, v, acc[2]); acc[3] = fmaf(wa.w, v, acc[3]);
            acc[4] = fmaf(wb.x, v, acc[4]); acc[5] = fmaf(wb.y, v, acc[5]);
            acc[6] = fmaf(wb.z, v, acc[6]); acc[7] = fmaf(wb.w, v, acc[7]);
        }
        // slot (p*32 + lt) == (wv*64 + l): conflict-free stride-9 writes
        float* pp = &part[(wv * 64 + l) * 9];
#pragma unroll
        for (int j = 0; j < 8; ++j) pp[j] = acc[j];
    }
    __syncthreads();

    // ---- ph2: lanes 0-31 finalize z_e (bias + 4 partials ascending) ----
    if (tid < 32) {
        float ze[8];
#pragma unroll
        for (int j = 0; j < 8; ++j)
            ze[j] = b_in[j] + part[tid * 9 + j] + part[(32 + tid) * 9 + j]
                  + part[(64 + tid) * 9 + j] + part[(96 + tid) * 9 + j];
        float nrm2 = ze[0] * ze[0] + ze[1] * ze[1] + ze[2] * ze[2] + ze[3] * ze[3]
                   + ze[4] * ze[4] + ze[5] * ze[5] + ze[6] * ze[6] + ze[7] * ze[7];
        float zen = fmaxf(sqrtf(nrm2), 1e-12f);
        float r = 1.0f / zen;
        float e0 = ze[0] * r, e1 = ze[1] * r, e2 = ze[2] * r, e3 = ze[3] * r;
        float e4 = ze[4] * r, e5 = ze[5] * r, e6 = ze[6] * r, e7 = ze[7] * r;
        float a = e0 * e0 + e1 * e1 + e2 * e2 + e3 * e3
                + e4 * e4 + e5 * e5 + e6 * e6 + e7 * e7;
        float* ep = &enorm[tid * 12];
        ep[0] = e0; ep[1] = e1; ep[2] = e2; ep[3] = e3;
        ep[4] = e4; ep[5] = e5; ep[6] = e6; ep[7] = e7;
        ep[8] = a; ep[9] = nrm2; ep[10] = zen; ep[11] = 0.f;
    }

    // ---- load 8 neg-codebook entries/lane: e = wv*512 + k*64 + l ----
    float nc[8][8]; float c2[8];
    int ebase = wv * 512;
#pragma unroll
    for (int k = 0; k < 8; ++k) {
        int e = ebase + k * 64 + l;
        const float4* p = (const float4*)(ws + WS_NCB + (size_t)e * 8);
        float4 p0 = p[0], p1 = p[1];
        nc[k][0] = p0.x; nc[k][1] = p0.y; nc[k][2] = p0.z; nc[k][3] = p0.w;
        nc[k][4] = p1.x; nc[k][5] = p1.y; nc[k][6] = p1.z; nc[k][7] = p1.w;
        c2[k] = ws[WS_QT + (size_t)e * 4 + 2];
    }
    __syncthreads();

    // ---- ph3: score = cc/2 - dot (argmin-equivalent); butterfly lex-min ----
    for (int s = 0; s < 32; ++s) {
        float4 E0 = ((float4*)enorm)[s * 3 + 0];
        float4 E1 = ((float4*)enorm)[s * 3 + 1];
        float sb = 3.4e38f; int bi = 0x7fffffff;
#pragma unroll
        for (int k = 0; k < 8; ++k) {
            float sc = fmaf(nc[k][0], E0.x, c2[k]);
            sc = fmaf(nc[k][1], E0.y, sc);
            sc = fmaf(nc[k][2], E0.z, sc);
            sc = fmaf(nc[k][3], E0.w, sc);
            sc = fmaf(nc[k][4], E1.x, sc);
            sc = fmaf(nc[k][5], E1.y, sc);
            sc = fmaf(nc[k][6], E1.z, sc);
            sc = fmaf(nc[k][7], E1.w, sc);
            int e = ebase + k * 64 + l;
            if (sc < sb) { sb = sc; bi = e; }   // strict < -> first-min
        }
#pragma unroll
        for (int off = 1; off < 64; off <<= 1) {
            float ov = __shfl_xor(sb, off, 64);
            int   oi = __shfl_xor(bi, off, 64);
            if (ov < sb || (ov == sb && oi < bi)) { sb = ov; bi = oi; }
        }
        if (l == 0) { cand_d[wv * 32 + s] = sb; cand_i[wv * 32 + s] = bi; }
    }
    __syncthreads();

    // ---- ph4: lanes 0-31 merge the two waves + loss, one parallel pass ----
    if (tid < 32) {
        float d0 = cand_d[tid];       int i0 = cand_i[tid];
        float d1 = cand_d[32 + tid];  int i1 = cand_i[32 + tid];
        if (d1 < d0) { d0 = d1; i0 = i1; }   // ranges disjoint; wave0 wins ties
        idxl[tid] = i0;
        int tok = blk * 32 + tid;
        d_out[OUT_OFF_IDX + tok] = (float)i0;
        float nrm2 = enorm[tid * 12 + 9], zen = enorm[tid * 12 + 10];
        float4 qt = ((const float4*)(ws + WS_QT))[i0];   // {qn, sw, cc2, 0}
        float dot = qt.z - d0;
        float lv = nrm2 - 2.0f * dot * zen * qt.x + qt.y;
#pragma unroll
        for (int off = 1; off < 32; off <<= 1) lv += __shfl_xor(lv, off, 64);
        if (tid == 0) bpart[blk] = lv;
    }
    __syncthreads();

    // ---- ph5: pcb-gather out; q = tid>>5 row quarter, tk = tid&31 token ----
    {
        int tk = tid & 31, q = tid >> 5;
        int idx = idxl[tk];
        const float4* pr = (const float4*)(ws + WS_PCB + (size_t)idx * 512 + q * 128);
        float* op = d_out + (size_t)b * D_ * T_ + (size_t)(q * 128) * T_ + tb + tk;
#pragma unroll 8
        for (int k = 0; k < 32; ++k) {
            float4 v = pr[k];
            op[(size_t)(k * 4 + 0) * T_] = v.x;
            op[(size_t)(k * 4 + 1) * T_] = v.y;
            op[(size_t)(k * 4 + 2) * T_] = v.z;
            op[(size_t)(k * 4 + 3) * T_] = v.w;
        }
    }
}

// ============ finalize: per-batch loss reduction =============================
__global__ __launch_bounds__(64) void vq_finalize(const float* __restrict__ bpart,
                                                  float* __restrict__ d_out) {
    int tid = threadIdx.x;
    if (tid < B_) {
        float s = 0.f;
        for (int k = 0; k < 128; ++k) s += bpart[tid * 128 + k];
        float m = s * (1.0f / (CD_ * T_));
        d_out[OUT_OFF_LOSS + tid] = m;
        d_out[OUT_OFF_LOSS + 16 + tid] = m;
    }
}

// ---------------- launch -----------------------------------------------------
extern "C" void kernel_launch(void* const* d_in, const int* in_sizes, int n_in,
                              void* d_out, int out_size, void* d_ws, size_t ws_size,
                              hipStream_t stream) {
    (void)in_sizes; (void)n_in; (void)out_size; (void)ws_size;
    const float* z        = (const float*)d_in[0];
    const float* v_in     = (const float*)d_in[1];
    const float* g_in     = (const float*)d_in[2];
    const float* b_in     = (const float*)d_in[3];
    const float* v_out    = (const float*)d_in[4];
    const float* g_out    = (const float*)d_in[5];
    const float* b_out    = (const float*)d_in[6];
    const float* codebook = (const float*)d_in[7];
    float* ws  = (float*)d_ws;
    float* out = (float*)d_out;

    hipLaunchKernelGGL(k0_prep, dim3(5 + CBN_), dim3(256), 0, stream,
                       v_in, g_in, v_out, g_out, b_out, codebook, ws);
    hipLaunchKernelGGL(vq_main, dim3(NTOK_ / 32), dim3(128), 0, stream,
                       z, b_in, ws, out, ws + WS_BPART);
    hipLaunchKernelGGL(vq_finalize, dim3(1), dim3(64), 0, stream,
                       ws + WS_BPART, out);
}